// Round 12
// baseline (155.923 us; speedup 1.0000x reference)
//
#include <hip/hip_runtime.h>
#include <math.h>

#define G 4
#define NN 1024
#define FF 256
#define HH 256
#define BB 32
#define LL 4

typedef __attribute__((ext_vector_type(8))) short short8;
typedef __attribute__((ext_vector_type(8))) unsigned short ushort8;
typedef __attribute__((ext_vector_type(4))) unsigned short ushort4v;
typedef __attribute__((ext_vector_type(4))) float floatx4;

__device__ inline unsigned short f2bf(float f) {
  union { float f; unsigned u; } x; x.f = f;
  unsigned r = x.u + 0x7fffu + ((x.u >> 16) & 1u);  // RNE
  return (unsigned short)(r >> 16);
}
__device__ inline float bf2f(unsigned short u) {
  union { unsigned u; float f; } x; x.u = (unsigned)u << 16;
  return x.f;
}

// ---- in tile: h0 = relu(X @ w_in + b_in) -> h0bf (bf16 [m][n])
__device__ void in_tile(int job, const float* __restrict__ X,
                        const float* __restrict__ w_in,
                        const float* __restrict__ b_in,
                        unsigned short* __restrict__ h0bf, unsigned short* As,
                        unsigned short* Bs, int t) {
  const int nt_ = job & 3, mt = (job >> 2) & 15, g = job >> 6;
  const int m0 = mt * 64, n0 = nt_ * 64;
  const int lane = t & 63, w = t >> 6;
  const int wm = w & 1, wn = w >> 1;
  const int l16 = lane & 15, quad = lane >> 4;

  floatx4 acc[2][2];
#pragma unroll
  for (int i = 0; i < 2; ++i)
#pragma unroll
    for (int j = 0; j < 2; ++j) acc[i][j] = (floatx4){0.f, 0.f, 0.f, 0.f};

  for (int tt = 0; tt < 4; ++tt) {
    const int kb = tt * 64;
    __syncthreads();
#pragma unroll
    for (int i = 0; i < 2; ++i) {
      const int q = t + i * 256;
      const int row = q >> 3, c8 = q & 7;
      const float* Af =
          X + (long)g * NN * FF + (long)(m0 + row) * FF + kb + c8 * 8;
      float4 f0 = *(const float4*)Af;
      float4 f1 = *(const float4*)(Af + 4);
      ushort8 v;
      v[0] = f2bf(f0.x); v[1] = f2bf(f0.y); v[2] = f2bf(f0.z); v[3] = f2bf(f0.w);
      v[4] = f2bf(f1.x); v[5] = f2bf(f1.y); v[6] = f2bf(f1.z); v[7] = f2bf(f1.w);
      *(ushort8*)&As[row * 72 + c8 * 8] = v;
    }
    {  // w_in fp32 [k][n] -> Bs[n][k] (LDS transpose)
      const int row = t >> 2;
      const int c0 = (t & 3) * 16;
#pragma unroll
      for (int j = 0; j < 4; ++j) {
        float4 f = *(const float4*)&w_in[(long)(kb + row) * HH + n0 + c0 + j * 4];
        Bs[(c0 + j * 4 + 0) * 72 + row] = f2bf(f.x);
        Bs[(c0 + j * 4 + 1) * 72 + row] = f2bf(f.y);
        Bs[(c0 + j * 4 + 2) * 72 + row] = f2bf(f.z);
        Bs[(c0 + j * 4 + 3) * 72 + row] = f2bf(f.w);
      }
    }
    __syncthreads();
#pragma unroll
    for (int kk = 0; kk < 64; kk += 32) {
      const int ko = kk + quad * 8;
      short8 a0 = *(const short8*)&As[(wm * 32 + l16) * 72 + ko];
      short8 a1 = *(const short8*)&As[(wm * 32 + 16 + l16) * 72 + ko];
      short8 b0 = *(const short8*)&Bs[(wn * 32 + l16) * 72 + ko];
      short8 b1 = *(const short8*)&Bs[(wn * 32 + 16 + l16) * 72 + ko];
      acc[0][0] = __builtin_amdgcn_mfma_f32_16x16x32_bf16(a0, b0, acc[0][0], 0, 0, 0);
      acc[0][1] = __builtin_amdgcn_mfma_f32_16x16x32_bf16(a0, b1, acc[0][1], 0, 0, 0);
      acc[1][0] = __builtin_amdgcn_mfma_f32_16x16x32_bf16(a1, b0, acc[1][0], 0, 0, 0);
      acc[1][1] = __builtin_amdgcn_mfma_f32_16x16x32_bf16(a1, b1, acc[1][1], 0, 0, 0);
    }
  }

#pragma unroll
  for (int i = 0; i < 2; ++i) {
#pragma unroll
    for (int j = 0; j < 2; ++j) {
      const int n = n0 + wn * 32 + j * 16 + l16;
      const int mB = m0 + wm * 32 + i * 16 + quad * 4;
      const float bv = b_in[n];
#pragma unroll
      for (int r = 0; r < 4; ++r)
        h0bf[(long)g * NN * HH + (long)(mB + r) * HH + n] =
            f2bf(fmaxf(acc[i][j][r] + bv, 0.f));
    }
  }
}

// ---- misc jobs (round-8..11 verified) ----
__device__ void mask_job(int b, const void* __restrict__ cp_mask,
                         float* __restrict__ fmask, float* __restrict__ denom,
                         int t) {
  const unsigned char* bytes = (const unsigned char*)cp_mask;
  __shared__ int fmt;
  __shared__ float red[256];
  if (t == 0) {
    int any = 0;
    for (int i = 0; i < 256; ++i)
      if ((i & 3) && bytes[i]) any = 1;
    fmt = any ? 0 : 1;
  }
  __syncthreads();
  float cnt = 0.f;
  for (int n = t; n < NN; n += 256) {
    float v;
    if (fmt)
      v = ((const int*)cp_mask)[b * NN + n] ? 1.f : 0.f;
    else
      v = bytes[b * NN + n] ? 1.f : 0.f;
    fmask[b * NN + n] = v;
    cnt += v;
  }
  red[t] = cnt;
  __syncthreads();
  for (int s = 128; s > 0; s >>= 1) {
    if (t < s) red[t] += red[t + s];
    __syncthreads();
  }
  if (t == 0) denom[b] = fmaxf(red[0], 1.f);
}

__device__ void gw_job(int j, const float* __restrict__ gcn_w,
                       unsigned short* __restrict__ gwT, int t) {
  const int l = j >> 4, r0 = (j & 15) * 16;
  const float* src = gcn_w + (long)l * HH * HH;
  unsigned short* dst = gwT + (long)l * HH * HH;
  unsigned short vv[16];
#pragma unroll
  for (int rr = 0; rr < 16; ++rr) vv[rr] = f2bf(src[(long)(r0 + rr) * HH + t]);
  *(ushort8*)&dst[(long)t * HH + r0] = *(ushort8*)&vv[0];
  *(ushort8*)&dst[(long)t * HH + r0 + 8] = *(ushort8*)&vv[8];
}

// ---------------------------------------------------------------------------
// pre_kernel: [0,1024) A fp32->bf16; [1024,1280) input GEMM; [1280,1344)
// gwT transposes; [1344,1376) mask; 1376 zero-out.
// ---------------------------------------------------------------------------
__global__ __launch_bounds__(256) void pre_kernel(
    const float* __restrict__ batch_as, unsigned short* __restrict__ Abf,
    const float* __restrict__ batch_xs, const float* __restrict__ w_in,
    const float* __restrict__ b_in, unsigned short* __restrict__ h0bf,
    const float* __restrict__ gcn_w, unsigned short* __restrict__ gwT,
    const void* __restrict__ cp_mask, float* __restrict__ fmask,
    float* __restrict__ denom, float* __restrict__ out) {
  __shared__ __align__(16) unsigned short As[64 * 72];
  __shared__ __align__(16) unsigned short Bs[64 * 72];
  const int b = blockIdx.x, t = threadIdx.x;
  if (b < 1024) {
    const long idx = ((long)b * 256 + t) * 16;
#pragma unroll
    for (int h = 0; h < 2; ++h) {
      float4 f0 = *(const float4*)&batch_as[idx + h * 8];
      float4 f1 = *(const float4*)&batch_as[idx + h * 8 + 4];
      ushort8 v;
      v[0] = f2bf(f0.x); v[1] = f2bf(f0.y); v[2] = f2bf(f0.z); v[3] = f2bf(f0.w);
      v[4] = f2bf(f1.x); v[5] = f2bf(f1.y); v[6] = f2bf(f1.z); v[7] = f2bf(f1.w);
      *(ushort8*)&Abf[idx + h * 8] = v;
    }
  } else if (b < 1280) {
    in_tile(b - 1024, batch_xs, w_in, b_in, h0bf, As, Bs, t);
  } else if (b < 1344) {
    gw_job(b - 1280, gcn_w, gwT, t);
  } else if (b < 1376) {
    mask_job(b - 1344, cp_mask, fmask, denom, t);
  } else {
    for (int i = 0; i < 32; ++i) out[i * 256 + t] = 0.f;
  }
}

// ---------------------------------------------------------------------------
// g1: yT = (x @ W_l)^T bf16 [g][n][m]. 64x64 tile, register prefetch.
// AM==0: A = h0bf (bf16 [m][k]).
// AM==2: A = relu(T0 + T1 + biasA) from bf16 split-K partials (fuses the
//        previous g2s reduction + bias + relu into staging).
// ---------------------------------------------------------------------------
template <int AM>
__global__ __launch_bounds__(256) void g1_kernel(
    const unsigned short* __restrict__ Xa, const unsigned short* __restrict__ T1,
    const float* __restrict__ biasA, const unsigned short* __restrict__ WT,
    unsigned short* __restrict__ yT) {
  __shared__ __align__(16) unsigned short As[64 * 72];
  __shared__ __align__(16) unsigned short Bs[64 * 72];
  const int n0 = blockIdx.x * 64;
  const int m0 = blockIdx.y * 64;
  const int g = blockIdx.z;
  const int t = threadIdx.x;
  const int lane = t & 63, w = t >> 6;
  const int wm = w & 1, wn = w >> 1;
  const int l16 = lane & 15, quad = lane >> 4;

  const unsigned short* A0 = Xa + (long)g * NN * HH;
  const unsigned short* A1 = AM == 2 ? T1 + (long)g * NN * HH : nullptr;

  ushort8 pa[2], pa2[2], pb[2];
  auto load_tile = [&](int tt) {
    const int kb = tt * 64;
#pragma unroll
    for (int i = 0; i < 2; ++i) {
      const int q = t + i * 256;
      const int row = q >> 3, c8 = q & 7;
      pa[i] = *(const ushort8*)&A0[(long)(m0 + row) * HH + kb + c8 * 8];
      if (AM == 2)
        pa2[i] = *(const ushort8*)&A1[(long)(m0 + row) * HH + kb + c8 * 8];
      pb[i] = *(const ushort8*)&WT[(long)(n0 + row) * HH + kb + c8 * 8];
    }
  };
  auto store_tile = [&](int tt) {
    const int kb = tt * 64;
#pragma unroll
    for (int i = 0; i < 2; ++i) {
      const int q = t + i * 256;
      const int row = q >> 3, c8 = q & 7;
      ushort8 v;
      if (AM == 0) {
        v = pa[i];
      } else {
        float4 bb0 = *(const float4*)&biasA[kb + c8 * 8];
        float4 bb1 = *(const float4*)&biasA[kb + c8 * 8 + 4];
        float bb[8] = {bb0.x, bb0.y, bb0.z, bb0.w, bb1.x, bb1.y, bb1.z, bb1.w};
#pragma unroll
        for (int j = 0; j < 8; ++j)
          v[j] = f2bf(fmaxf(bf2f(pa[i][j]) + bf2f(pa2[i][j]) + bb[j], 0.f));
      }
      *(ushort8*)&As[row * 72 + c8 * 8] = v;
      *(ushort8*)&Bs[row * 72 + c8 * 8] = pb[i];
    }
  };

  floatx4 acc[2][2];
#pragma unroll
  for (int i = 0; i < 2; ++i)
#pragma unroll
    for (int j = 0; j < 2; ++j) acc[i][j] = (floatx4){0.f, 0.f, 0.f, 0.f};

  load_tile(0);
  for (int tt = 0; tt < 4; ++tt) {
    __syncthreads();
    store_tile(tt);
    __syncthreads();
    if (tt + 1 < 4) load_tile(tt + 1);
#pragma unroll
    for (int kk = 0; kk < 64; kk += 32) {
      const int ko = kk + quad * 8;
      short8 a0 = *(const short8*)&As[(wm * 32 + l16) * 72 + ko];
      short8 a1 = *(const short8*)&As[(wm * 32 + 16 + l16) * 72 + ko];
      short8 b0 = *(const short8*)&Bs[(wn * 32 + l16) * 72 + ko];
      short8 b1 = *(const short8*)&Bs[(wn * 32 + 16 + l16) * 72 + ko];
      acc[0][0] = __builtin_amdgcn_mfma_f32_16x16x32_bf16(a0, b0, acc[0][0], 0, 0, 0);
      acc[0][1] = __builtin_amdgcn_mfma_f32_16x16x32_bf16(a0, b1, acc[0][1], 0, 0, 0);
      acc[1][0] = __builtin_amdgcn_mfma_f32_16x16x32_bf16(a1, b0, acc[1][0], 0, 0, 0);
      acc[1][1] = __builtin_amdgcn_mfma_f32_16x16x32_bf16(a1, b1, acc[1][1], 0, 0, 0);
    }
  }

#pragma unroll
  for (int i = 0; i < 2; ++i) {
#pragma unroll
    for (int j = 0; j < 2; ++j) {
      const int n = n0 + wn * 32 + j * 16 + l16;
      const int mB = m0 + wm * 32 + i * 16 + quad * 4;
      ushort4v pv;
#pragma unroll
      for (int r = 0; r < 4; ++r) pv[r] = f2bf(acc[i][j][r]);
      *(ushort4v*)&yT[(long)g * HH * NN + (long)n * NN + mB] = pv;
    }
  }
}

// ---------------------------------------------------------------------------
// g2s (relu layers): T[half] = A[g][:, half] @ y[g][half, :] bf16 partials.
// 64x64 tile, split-K=2 (grid (4,16,8) = 512 blocks = 2 blocks/CU), BK=128,
// 4 waves of 32x32 (2x2 frags: 4 ds_read per 4 MFMA — 1:1), reg prefetch.
// ---------------------------------------------------------------------------
__global__ __launch_bounds__(256) void g2s_kernel(
    const unsigned short* __restrict__ Abf,
    const unsigned short* __restrict__ yT, unsigned short* __restrict__ Tp) {
  __shared__ __align__(16) unsigned short As[64 * 136];
  __shared__ __align__(16) unsigned short Bs[64 * 136];
  const int z = blockIdx.z;
  const int g = z & 3, half = z >> 2;
  const int koff = half * (NN / 2);
  const int n0 = blockIdx.x * 64;
  const int m0 = blockIdx.y * 64;
  const int t = threadIdx.x;
  const int lane = t & 63, w = t >> 6;
  const int wm = w & 1, wn = w >> 1;
  const int l16 = lane & 15, quad = lane >> 4;

  const unsigned short* Ag = Abf + (long)g * NN * NN + (long)m0 * NN + koff;
  const unsigned short* Bg = yT + (long)g * HH * NN + (long)n0 * NN + koff;

  ushort8 pa[4], pb[4];
  auto load_tile = [&](int tt) {
    const int kb = tt * 128;
#pragma unroll
    for (int i = 0; i < 4; ++i) {
      const int q = t + i * 256;
      const int row = q >> 4, c8 = q & 15;
      pa[i] = *(const ushort8*)&Ag[(long)row * NN + kb + c8 * 8];
      pb[i] = *(const ushort8*)&Bg[(long)row * NN + kb + c8 * 8];
    }
  };
  auto store_tile = [&]() {
#pragma unroll
    for (int i = 0; i < 4; ++i) {
      const int q = t + i * 256;
      const int row = q >> 4, c8 = q & 15;
      *(ushort8*)&As[row * 136 + c8 * 8] = pa[i];
      *(ushort8*)&Bs[row * 136 + c8 * 8] = pb[i];
    }
  };

  floatx4 acc[2][2];
#pragma unroll
  for (int i = 0; i < 2; ++i)
#pragma unroll
    for (int j = 0; j < 2; ++j) acc[i][j] = (floatx4){0.f, 0.f, 0.f, 0.f};

  load_tile(0);
  for (int tt = 0; tt < 4; ++tt) {
    __syncthreads();
    store_tile();
    __syncthreads();
    if (tt + 1 < 4) load_tile(tt + 1);
#pragma unroll
    for (int kk = 0; kk < 128; kk += 32) {
      const int ko = kk + quad * 8;
      short8 a0 = *(const short8*)&As[(wm * 32 + l16) * 136 + ko];
      short8 a1 = *(const short8*)&As[(wm * 32 + 16 + l16) * 136 + ko];
      short8 b0 = *(const short8*)&Bs[(wn * 32 + l16) * 136 + ko];
      short8 b1 = *(const short8*)&Bs[(wn * 32 + 16 + l16) * 136 + ko];
      acc[0][0] = __builtin_amdgcn_mfma_f32_16x16x32_bf16(a0, b0, acc[0][0], 0, 0, 0);
      acc[0][1] = __builtin_amdgcn_mfma_f32_16x16x32_bf16(a0, b1, acc[0][1], 0, 0, 0);
      acc[1][0] = __builtin_amdgcn_mfma_f32_16x16x32_bf16(a1, b0, acc[1][0], 0, 0, 0);
      acc[1][1] = __builtin_amdgcn_mfma_f32_16x16x32_bf16(a1, b1, acc[1][1], 0, 0, 0);
    }
  }

  unsigned short* Tz = Tp + ((long)half * G + g) * NN * HH;
#pragma unroll
  for (int i = 0; i < 2; ++i) {
#pragma unroll
    for (int j = 0; j < 2; ++j) {
      const int n = n0 + wn * 32 + j * 16 + l16;
      const int mB = m0 + wm * 32 + i * 16 + quad * 4;
#pragma unroll
      for (int r = 0; r < 4; ++r)
        Tz[(long)(mB + r) * HH + n] = f2bf(acc[i][j][r]);
    }
  }
}

// ---------------------------------------------------------------------------
// g2f (final layer): T = A @ y full K=1024, BK=128, 32x64 tile, 512 blocks.
// Fused: z = tanh(T + bias) + h0bf, then masked mean into out via
// quad-butterfly shfl + one atomic per (b, feature) per wm-half.
// (round-11 verified)
// ---------------------------------------------------------------------------
__global__ __launch_bounds__(256) void g2f_kernel(
    const unsigned short* __restrict__ Abf,
    const unsigned short* __restrict__ yT, const float* __restrict__ bias,
    const unsigned short* __restrict__ h0bf, const float* __restrict__ fmask,
    const float* __restrict__ denom, const int* __restrict__ gidx,
    float* __restrict__ out) {
  __shared__ __align__(16) unsigned short As[32 * 136];
  __shared__ __align__(16) unsigned short Bs[64 * 136];
  const int n0 = blockIdx.x * 64;
  const int m0 = blockIdx.y * 32;
  const int g = blockIdx.z;
  const int t = threadIdx.x;
  const int lane = t & 63, w = t >> 6;
  const int wm = w & 1, wn = w >> 1;
  const int l16 = lane & 15, quad = lane >> 4;

  const unsigned short* Ag = Abf + (long)g * NN * NN + (long)m0 * NN;
  const unsigned short* Bg = yT + (long)g * HH * NN + (long)n0 * NN;

  ushort8 pa[2], pb[4];
  auto load_tile = [&](int tt) {
    const int kb = tt * 128;
#pragma unroll
    for (int i = 0; i < 2; ++i) {
      const int q = t + i * 256;
      const int row = q >> 4, c8 = q & 15;
      pa[i] = *(const ushort8*)&Ag[(long)row * NN + kb + c8 * 8];
    }
#pragma unroll
    for (int i = 0; i < 4; ++i) {
      const int q = t + i * 256;
      const int row = q >> 4, c8 = q & 15;
      pb[i] = *(const ushort8*)&Bg[(long)row * NN + kb + c8 * 8];
    }
  };
  auto store_tile = [&]() {
#pragma unroll
    for (int i = 0; i < 2; ++i) {
      const int q = t + i * 256;
      const int row = q >> 4, c8 = q & 15;
      *(ushort8*)&As[row * 136 + c8 * 8] = pa[i];
    }
#pragma unroll
    for (int i = 0; i < 4; ++i) {
      const int q = t + i * 256;
      const int row = q >> 4, c8 = q & 15;
      *(ushort8*)&Bs[row * 136 + c8 * 8] = pb[i];
    }
  };

  floatx4 acc[2];
  acc[0] = (floatx4){0.f, 0.f, 0.f, 0.f};
  acc[1] = (floatx4){0.f, 0.f, 0.f, 0.f};

  load_tile(0);
  for (int tt = 0; tt < 8; ++tt) {
    __syncthreads();
    store_tile();
    __syncthreads();
    if (tt + 1 < 8) load_tile(tt + 1);
#pragma unroll
    for (int kk = 0; kk < 128; kk += 32) {
      const int ko = kk + quad * 8;
      short8 a = *(const short8*)&As[(wm * 16 + l16) * 136 + ko];
      short8 b0 = *(const short8*)&Bs[(wn * 32 + l16) * 136 + ko];
      short8 b1 = *(const short8*)&Bs[(wn * 32 + 16 + l16) * 136 + ko];
      acc[0] = __builtin_amdgcn_mfma_f32_16x16x32_bf16(a, b0, acc[0], 0, 0, 0);
      acc[1] = __builtin_amdgcn_mfma_f32_16x16x32_bf16(a, b1, acc[1], 0, 0, 0);
    }
  }

  // fused tanh + residual + masked mean
  const int mB0 = m0 + wm * 16 + quad * 4;
  float zv[2][4];
#pragma unroll
  for (int j = 0; j < 2; ++j) {
    const int n = n0 + wn * 32 + j * 16 + l16;
    const float bv = bias[n];
#pragma unroll
    for (int r = 0; r < 4; ++r) {
      const long idx = (long)g * NN * HH + (long)(mB0 + r) * HH + n;
      zv[j][r] = tanhf(acc[j][r] + bv) + bf2f(h0bf[idx]);
    }
  }
  for (int b = 0; b < BB; ++b) {
    if (gidx[b] != g) continue;  // block-uniform branch
    const float invd = 1.f / denom[b];
    float m4[4];
#pragma unroll
    for (int r = 0; r < 4; ++r) m4[r] = fmask[b * NN + mB0 + r];
#pragma unroll
    for (int j = 0; j < 2; ++j) {
      float p = m4[0] * zv[j][0] + m4[1] * zv[j][1] + m4[2] * zv[j][2] +
                m4[3] * zv[j][3];
      p += __shfl_xor(p, 16);
      p += __shfl_xor(p, 32);
      if (quad == 0) {
        const int n = n0 + wn * 32 + j * 16 + l16;
        atomicAdd(&out[b * HH + n], p * invd);
      }
    }
  }
}

extern "C" void kernel_launch(void* const* d_in, const int* in_sizes, int n_in,
                              void* d_out, int out_size, void* d_ws,
                              size_t ws_size, hipStream_t stream) {
  (void)in_sizes; (void)n_in; (void)out_size; (void)ws_size;
  const float* batch_xs = (const float*)d_in[0];
  const float* batch_as = (const float*)d_in[1];
  const float* w_in = (const float*)d_in[2];
  const float* b_in = (const float*)d_in[3];
  const float* gcn_w = (const float*)d_in[4];
  const float* gcn_b = (const float*)d_in[5];
  const int* graph_idx = (const int*)d_in[6];
  const void* cp_mask = d_in[7];
  float* out = (float*)d_out;

  char* p = (char*)d_ws;
  unsigned short* Abf = (unsigned short*)p;  p += (long)G * NN * NN * 2;
  unsigned short* gwT = (unsigned short*)p;  p += (long)LL * HH * HH * 2;
  unsigned short* h0bf = (unsigned short*)p; p += (long)G * NN * HH * 2;
  unsigned short* yT = (unsigned short*)p;   p += (long)G * HH * NN * 2;
  unsigned short* Tp = (unsigned short*)p;   p += 2L * G * NN * HH * 2;
  float* fmask = (float*)p;                  p += (long)BB * NN * 4;
  float* denom = (float*)p;                  p += BB * 4;
  unsigned short* Tp1 = Tp + (long)G * NN * HH;

  pre_kernel<<<1377, 256, 0, stream>>>(batch_as, Abf, batch_xs, w_in, b_in,
                                       h0bf, gcn_w, gwT, cp_mask, fmask,
                                       denom, out);

  for (int l = 0; l < LL; ++l) {
    if (l == 0)
      g1_kernel<0><<<dim3(4, 16, G), 256, 0, stream>>>(
          h0bf, nullptr, nullptr, gwT, yT);
    else
      g1_kernel<2><<<dim3(4, 16, G), 256, 0, stream>>>(
          Tp, Tp1, gcn_b + (long)(l - 1) * HH, gwT + (long)l * HH * HH, yT);

    if (l < LL - 1)
      g2s_kernel<<<dim3(4, 16, 8), 256, 0, stream>>>(Abf, yT, Tp);
    else
      g2f_kernel<<<dim3(4, 32, G), 256, 0, stream>>>(
          Abf, yT, gcn_b + (long)l * HH, h0bf, fmask, denom, graph_idx, out);
  }
}

// Round 13
// 149.460 us; speedup vs baseline: 1.0432x; 1.0432x over previous
//
#include <hip/hip_runtime.h>
#include <math.h>

#define G 4
#define NN 1024
#define FF 256
#define HH 256
#define BB 32
#define LL 4

typedef __attribute__((ext_vector_type(8))) short short8;
typedef __attribute__((ext_vector_type(8))) unsigned short ushort8;
typedef __attribute__((ext_vector_type(4))) unsigned short ushort4v;
typedef __attribute__((ext_vector_type(4))) float floatx4;

__device__ inline unsigned short f2bf(float f) {
  union { float f; unsigned u; } x; x.f = f;
  unsigned r = x.u + 0x7fffu + ((x.u >> 16) & 1u);  // RNE
  return (unsigned short)(r >> 16);
}
__device__ inline float bf2f(unsigned short u) {
  union { unsigned u; float f; } x; x.u = (unsigned)u << 16;
  return x.f;
}

// ---- in tile: x0 = relu(X @ w_in + b_in) -> xbf + h0bf (both bf16 [m][n])
__device__ void in_tile(int job, const float* __restrict__ X,
                        const float* __restrict__ w_in,
                        const float* __restrict__ b_in,
                        unsigned short* __restrict__ xbf,
                        unsigned short* __restrict__ h0bf, unsigned short* As,
                        unsigned short* Bs, int t) {
  const int nt_ = job & 3, mt = (job >> 2) & 15, g = job >> 6;
  const int m0 = mt * 64, n0 = nt_ * 64;
  const int lane = t & 63, w = t >> 6;
  const int wm = w & 1, wn = w >> 1;
  const int l16 = lane & 15, quad = lane >> 4;

  floatx4 acc[2][2];
#pragma unroll
  for (int i = 0; i < 2; ++i)
#pragma unroll
    for (int j = 0; j < 2; ++j) acc[i][j] = (floatx4){0.f, 0.f, 0.f, 0.f};

  for (int tt = 0; tt < 4; ++tt) {
    const int kb = tt * 64;
    __syncthreads();
#pragma unroll
    for (int i = 0; i < 2; ++i) {
      const int q = t + i * 256;
      const int row = q >> 3, c8 = q & 7;
      const float* Af =
          X + (long)g * NN * FF + (long)(m0 + row) * FF + kb + c8 * 8;
      float4 f0 = *(const float4*)Af;
      float4 f1 = *(const float4*)(Af + 4);
      ushort8 v;
      v[0] = f2bf(f0.x); v[1] = f2bf(f0.y); v[2] = f2bf(f0.z); v[3] = f2bf(f0.w);
      v[4] = f2bf(f1.x); v[5] = f2bf(f1.y); v[6] = f2bf(f1.z); v[7] = f2bf(f1.w);
      *(ushort8*)&As[row * 72 + c8 * 8] = v;
    }
    {  // w_in fp32 [k][n] -> Bs[n][k] (LDS transpose)
      const int row = t >> 2;
      const int c0 = (t & 3) * 16;
#pragma unroll
      for (int j = 0; j < 4; ++j) {
        float4 f = *(const float4*)&w_in[(long)(kb + row) * HH + n0 + c0 + j * 4];
        Bs[(c0 + j * 4 + 0) * 72 + row] = f2bf(f.x);
        Bs[(c0 + j * 4 + 1) * 72 + row] = f2bf(f.y);
        Bs[(c0 + j * 4 + 2) * 72 + row] = f2bf(f.z);
        Bs[(c0 + j * 4 + 3) * 72 + row] = f2bf(f.w);
      }
    }
    __syncthreads();
#pragma unroll
    for (int kk = 0; kk < 64; kk += 32) {
      const int ko = kk + quad * 8;
      short8 a0 = *(const short8*)&As[(wm * 32 + l16) * 72 + ko];
      short8 a1 = *(const short8*)&As[(wm * 32 + 16 + l16) * 72 + ko];
      short8 b0 = *(const short8*)&Bs[(wn * 32 + l16) * 72 + ko];
      short8 b1 = *(const short8*)&Bs[(wn * 32 + 16 + l16) * 72 + ko];
      acc[0][0] = __builtin_amdgcn_mfma_f32_16x16x32_bf16(a0, b0, acc[0][0], 0, 0, 0);
      acc[0][1] = __builtin_amdgcn_mfma_f32_16x16x32_bf16(a0, b1, acc[0][1], 0, 0, 0);
      acc[1][0] = __builtin_amdgcn_mfma_f32_16x16x32_bf16(a1, b0, acc[1][0], 0, 0, 0);
      acc[1][1] = __builtin_amdgcn_mfma_f32_16x16x32_bf16(a1, b1, acc[1][1], 0, 0, 0);
    }
  }

#pragma unroll
  for (int i = 0; i < 2; ++i) {
#pragma unroll
    for (int j = 0; j < 2; ++j) {
      const int n = n0 + wn * 32 + j * 16 + l16;
      const int mB = m0 + wm * 32 + i * 16 + quad * 4;
      const float bv = b_in[n];
#pragma unroll
      for (int r = 0; r < 4; ++r) {
        const unsigned short pv = f2bf(fmaxf(acc[i][j][r] + bv, 0.f));
        xbf[(long)g * NN * HH + (long)(mB + r) * HH + n] = pv;
        h0bf[(long)g * NN * HH + (long)(mB + r) * HH + n] = pv;
      }
    }
  }
}

// ---- misc jobs (round-8..11 verified) ----
__device__ void mask_job(int b, const void* __restrict__ cp_mask,
                         float* __restrict__ fmask, float* __restrict__ denom,
                         int t) {
  const unsigned char* bytes = (const unsigned char*)cp_mask;
  __shared__ int fmt;
  __shared__ float red[256];
  if (t == 0) {
    int any = 0;
    for (int i = 0; i < 256; ++i)
      if ((i & 3) && bytes[i]) any = 1;
    fmt = any ? 0 : 1;
  }
  __syncthreads();
  float cnt = 0.f;
  for (int n = t; n < NN; n += 256) {
    float v;
    if (fmt)
      v = ((const int*)cp_mask)[b * NN + n] ? 1.f : 0.f;
    else
      v = bytes[b * NN + n] ? 1.f : 0.f;
    fmask[b * NN + n] = v;
    cnt += v;
  }
  red[t] = cnt;
  __syncthreads();
  for (int s = 128; s > 0; s >>= 1) {
    if (t < s) red[t] += red[t + s];
    __syncthreads();
  }
  if (t == 0) denom[b] = fmaxf(red[0], 1.f);
}

__device__ void gw_job(int j, const float* __restrict__ gcn_w,
                       unsigned short* __restrict__ gwT, int t) {
  const int l = j >> 4, r0 = (j & 15) * 16;
  const float* src = gcn_w + (long)l * HH * HH;
  unsigned short* dst = gwT + (long)l * HH * HH;
  unsigned short vv[16];
#pragma unroll
  for (int rr = 0; rr < 16; ++rr) vv[rr] = f2bf(src[(long)(r0 + rr) * HH + t]);
  *(ushort8*)&dst[(long)t * HH + r0] = *(ushort8*)&vv[0];
  *(ushort8*)&dst[(long)t * HH + r0 + 8] = *(ushort8*)&vv[8];
}

// ---------------------------------------------------------------------------
// pre_kernel: [0,1024) A fp32->bf16 (16 el/thr); [1024,1280) input GEMM;
// [1280,1344) gwT transposes; [1344,1376) mask; 1376 zero-out.
// ---------------------------------------------------------------------------
__global__ __launch_bounds__(256) void pre_kernel(
    const float* __restrict__ batch_as, unsigned short* __restrict__ Abf,
    const float* __restrict__ batch_xs, const float* __restrict__ w_in,
    const float* __restrict__ b_in, unsigned short* __restrict__ xbf,
    unsigned short* __restrict__ h0bf, const float* __restrict__ gcn_w,
    unsigned short* __restrict__ gwT, const void* __restrict__ cp_mask,
    float* __restrict__ fmask, float* __restrict__ denom,
    float* __restrict__ out) {
  __shared__ __align__(16) unsigned short As[64 * 72];
  __shared__ __align__(16) unsigned short Bs[64 * 72];
  const int b = blockIdx.x, t = threadIdx.x;
  if (b < 1024) {
    const long idx = ((long)b * 256 + t) * 16;
#pragma unroll
    for (int h = 0; h < 2; ++h) {
      float4 f0 = *(const float4*)&batch_as[idx + h * 8];
      float4 f1 = *(const float4*)&batch_as[idx + h * 8 + 4];
      ushort8 v;
      v[0] = f2bf(f0.x); v[1] = f2bf(f0.y); v[2] = f2bf(f0.z); v[3] = f2bf(f0.w);
      v[4] = f2bf(f1.x); v[5] = f2bf(f1.y); v[6] = f2bf(f1.z); v[7] = f2bf(f1.w);
      *(ushort8*)&Abf[idx + h * 8] = v;
    }
  } else if (b < 1280) {
    in_tile(b - 1024, batch_xs, w_in, b_in, xbf, h0bf, As, Bs, t);
  } else if (b < 1344) {
    gw_job(b - 1280, gcn_w, gwT, t);
  } else if (b < 1376) {
    mask_job(b - 1344, cp_mask, fmask, denom, t);
  } else {
    for (int i = 0; i < 32; ++i) out[i * 256 + t] = 0.f;
  }
}

// ---------------------------------------------------------------------------
// g1: yT = (x @ W_l)^T bf16 [g][n][m]. 64x64 tile, register prefetch.
// ---------------------------------------------------------------------------
__global__ __launch_bounds__(256) void g1_kernel(
    const unsigned short* __restrict__ xbf,
    const unsigned short* __restrict__ WT,
    unsigned short* __restrict__ yT) {
  __shared__ __align__(16) unsigned short As[64 * 72];
  __shared__ __align__(16) unsigned short Bs[64 * 72];
  const int n0 = blockIdx.x * 64;
  const int m0 = blockIdx.y * 64;
  const int g = blockIdx.z;
  const int t = threadIdx.x;
  const int lane = t & 63, w = t >> 6;
  const int wm = w & 1, wn = w >> 1;
  const int l16 = lane & 15, quad = lane >> 4;

  const unsigned short* Ab = xbf + (long)g * NN * HH;

  ushort8 pa[2], pb[2];
  auto load_tile = [&](int tt) {
    const int kb = tt * 64;
#pragma unroll
    for (int i = 0; i < 2; ++i) {
      const int q = t + i * 256;
      const int row = q >> 3, c8 = q & 7;
      pa[i] = *(const ushort8*)&Ab[(long)(m0 + row) * HH + kb + c8 * 8];
      pb[i] = *(const ushort8*)&WT[(long)(n0 + row) * HH + kb + c8 * 8];
    }
  };
  auto store_tile = [&]() {
#pragma unroll
    for (int i = 0; i < 2; ++i) {
      const int q = t + i * 256;
      const int row = q >> 3, c8 = q & 7;
      *(ushort8*)&As[row * 72 + c8 * 8] = pa[i];
      *(ushort8*)&Bs[row * 72 + c8 * 8] = pb[i];
    }
  };

  floatx4 acc[2][2];
#pragma unroll
  for (int i = 0; i < 2; ++i)
#pragma unroll
    for (int j = 0; j < 2; ++j) acc[i][j] = (floatx4){0.f, 0.f, 0.f, 0.f};

  load_tile(0);
  for (int tt = 0; tt < 4; ++tt) {
    __syncthreads();
    store_tile();
    __syncthreads();
    if (tt + 1 < 4) load_tile(tt + 1);
#pragma unroll
    for (int kk = 0; kk < 64; kk += 32) {
      const int ko = kk + quad * 8;
      short8 a0 = *(const short8*)&As[(wm * 32 + l16) * 72 + ko];
      short8 a1 = *(const short8*)&As[(wm * 32 + 16 + l16) * 72 + ko];
      short8 b0 = *(const short8*)&Bs[(wn * 32 + l16) * 72 + ko];
      short8 b1 = *(const short8*)&Bs[(wn * 32 + 16 + l16) * 72 + ko];
      acc[0][0] = __builtin_amdgcn_mfma_f32_16x16x32_bf16(a0, b0, acc[0][0], 0, 0, 0);
      acc[0][1] = __builtin_amdgcn_mfma_f32_16x16x32_bf16(a0, b1, acc[0][1], 0, 0, 0);
      acc[1][0] = __builtin_amdgcn_mfma_f32_16x16x32_bf16(a1, b0, acc[1][0], 0, 0, 0);
      acc[1][1] = __builtin_amdgcn_mfma_f32_16x16x32_bf16(a1, b1, acc[1][1], 0, 0, 0);
    }
  }

#pragma unroll
  for (int i = 0; i < 2; ++i) {
#pragma unroll
    for (int j = 0; j < 2; ++j) {
      const int n = n0 + wn * 32 + j * 16 + l16;
      const int mB = m0 + wm * 32 + i * 16 + quad * 4;
      ushort4v pv;
#pragma unroll
      for (int r = 0; r < 4; ++r) pv[r] = f2bf(acc[i][j][r]);
      *(ushort4v*)&yT[(long)g * HH * NN + (long)n * NN + mB] = pv;
    }
  }
}

// ---------------------------------------------------------------------------
// g2: T = A @ y, full K=1024, BK=128 (8 barrier iterations).
// 32x64 tile, grid (4,32,4) = 512 blocks = 2 blocks/CU, register prefetch.
// ACT==1: xbf = relu(T + bias) bf16 (next layer input).
// ACT==0: fused final layer + masked mean:
//   z = tanh(T + bias) + h0bf;  for each example b with gidx[b]==g:
//   out[b,n] += (1/denom[b]) * sum_{nodes in tile} fmask[b,node]*z[node,n]
//   (quad-butterfly shfl reduction; one atomic per (b, n) per wm-half).
// ---------------------------------------------------------------------------
template <int ACT>
__global__ __launch_bounds__(256) void g2_kernel(
    const unsigned short* __restrict__ Abf,
    const unsigned short* __restrict__ yT, const float* __restrict__ bias,
    const unsigned short* __restrict__ h0bf, unsigned short* __restrict__ xbf,
    const float* __restrict__ fmask, const float* __restrict__ denom,
    const int* __restrict__ gidx, float* __restrict__ out) {
  __shared__ __align__(16) unsigned short As[32 * 136];
  __shared__ __align__(16) unsigned short Bs[64 * 136];
  const int n0 = blockIdx.x * 64;
  const int m0 = blockIdx.y * 32;
  const int g = blockIdx.z;
  const int t = threadIdx.x;
  const int lane = t & 63, w = t >> 6;
  const int wm = w & 1, wn = w >> 1;
  const int l16 = lane & 15, quad = lane >> 4;

  const unsigned short* Ag = Abf + (long)g * NN * NN + (long)m0 * NN;
  const unsigned short* Bg = yT + (long)g * HH * NN + (long)n0 * NN;

  ushort8 pa[2], pb[4];
  auto load_tile = [&](int tt) {
    const int kb = tt * 128;
#pragma unroll
    for (int i = 0; i < 2; ++i) {  // A: 32 rows x 128 k
      const int q = t + i * 256;
      const int row = q >> 4, c8 = q & 15;
      pa[i] = *(const ushort8*)&Ag[(long)row * NN + kb + c8 * 8];
    }
#pragma unroll
    for (int i = 0; i < 4; ++i) {  // B: 64 rows x 128 k
      const int q = t + i * 256;
      const int row = q >> 4, c8 = q & 15;
      pb[i] = *(const ushort8*)&Bg[(long)row * NN + kb + c8 * 8];
    }
  };
  auto store_tile = [&]() {
#pragma unroll
    for (int i = 0; i < 2; ++i) {
      const int q = t + i * 256;
      const int row = q >> 4, c8 = q & 15;
      *(ushort8*)&As[row * 136 + c8 * 8] = pa[i];
    }
#pragma unroll
    for (int i = 0; i < 4; ++i) {
      const int q = t + i * 256;
      const int row = q >> 4, c8 = q & 15;
      *(ushort8*)&Bs[row * 136 + c8 * 8] = pb[i];
    }
  };

  floatx4 acc[2];
  acc[0] = (floatx4){0.f, 0.f, 0.f, 0.f};
  acc[1] = (floatx4){0.f, 0.f, 0.f, 0.f};

  load_tile(0);
  for (int tt = 0; tt < 8; ++tt) {
    __syncthreads();
    store_tile();
    __syncthreads();
    if (tt + 1 < 8) load_tile(tt + 1);
#pragma unroll
    for (int kk = 0; kk < 128; kk += 32) {
      const int ko = kk + quad * 8;
      short8 a = *(const short8*)&As[(wm * 16 + l16) * 136 + ko];
      short8 b0 = *(const short8*)&Bs[(wn * 32 + l16) * 136 + ko];
      short8 b1 = *(const short8*)&Bs[(wn * 32 + 16 + l16) * 136 + ko];
      acc[0] = __builtin_amdgcn_mfma_f32_16x16x32_bf16(a, b0, acc[0], 0, 0, 0);
      acc[1] = __builtin_amdgcn_mfma_f32_16x16x32_bf16(a, b1, acc[1], 0, 0, 0);
    }
  }

  if (ACT == 1) {
#pragma unroll
    for (int j = 0; j < 2; ++j) {
      const int n = n0 + wn * 32 + j * 16 + l16;
      const int mB = m0 + wm * 16 + quad * 4;
      const float bv = bias[n];
#pragma unroll
      for (int r = 0; r < 4; ++r)
        xbf[(long)g * NN * HH + (long)(mB + r) * HH + n] =
            f2bf(fmaxf(acc[j][r] + bv, 0.f));
    }
  } else {
    // fused tanh + residual + masked mean
    const int mB0 = m0 + wm * 16 + quad * 4;
    float zv[2][4];
#pragma unroll
    for (int j = 0; j < 2; ++j) {
      const int n = n0 + wn * 32 + j * 16 + l16;
      const float bv = bias[n];
#pragma unroll
      for (int r = 0; r < 4; ++r) {
        const long idx = (long)g * NN * HH + (long)(mB0 + r) * HH + n;
        zv[j][r] = tanhf(acc[j][r] + bv) + bf2f(h0bf[idx]);
      }
    }
    for (int b = 0; b < BB; ++b) {
      if (gidx[b] != g) continue;  // block-uniform branch
      const float invd = 1.f / denom[b];
      float m4[4];
#pragma unroll
      for (int r = 0; r < 4; ++r) m4[r] = fmask[b * NN + mB0 + r];
#pragma unroll
      for (int j = 0; j < 2; ++j) {
        float p = m4[0] * zv[j][0] + m4[1] * zv[j][1] + m4[2] * zv[j][2] +
                  m4[3] * zv[j][3];
        p += __shfl_xor(p, 16);  // sum over quad bit 0
        p += __shfl_xor(p, 32);  // sum over quad bit 1
        if (quad == 0) {
          const int n = n0 + wn * 32 + j * 16 + l16;
          atomicAdd(&out[b * HH + n], p * invd);
        }
      }
    }
  }
}

extern "C" void kernel_launch(void* const* d_in, const int* in_sizes, int n_in,
                              void* d_out, int out_size, void* d_ws,
                              size_t ws_size, hipStream_t stream) {
  (void)in_sizes; (void)n_in; (void)out_size; (void)ws_size;
  const float* batch_xs = (const float*)d_in[0];
  const float* batch_as = (const float*)d_in[1];
  const float* w_in = (const float*)d_in[2];
  const float* b_in = (const float*)d_in[3];
  const float* gcn_w = (const float*)d_in[4];
  const float* gcn_b = (const float*)d_in[5];
  const int* graph_idx = (const int*)d_in[6];
  const void* cp_mask = d_in[7];
  float* out = (float*)d_out;

  char* p = (char*)d_ws;
  unsigned short* Abf = (unsigned short*)p;  p += (long)G * NN * NN * 2;
  unsigned short* gwT = (unsigned short*)p;  p += (long)LL * HH * HH * 2;
  unsigned short* xbf = (unsigned short*)p;  p += (long)G * NN * HH * 2;
  unsigned short* h0bf = (unsigned short*)p; p += (long)G * NN * HH * 2;
  unsigned short* yT = (unsigned short*)p;   p += (long)G * HH * NN * 2;
  float* fmask = (float*)p;                  p += (long)BB * NN * 4;
  float* denom = (float*)p;                  p += BB * 4;

  pre_kernel<<<1377, 256, 0, stream>>>(batch_as, Abf, batch_xs, w_in, b_in,
                                       xbf, h0bf, gcn_w, gwT, cp_mask, fmask,
                                       denom, out);

  for (int l = 0; l < LL; ++l) {
    g1_kernel<<<dim3(4, 16, G), 256, 0, stream>>>(
        xbf, gwT + (long)l * HH * HH, yT);
    if (l < LL - 1)
      g2_kernel<1><<<dim3(4, 32, G), 256, 0, stream>>>(
          Abf, yT, gcn_b + (long)l * HH, nullptr, xbf, nullptr, nullptr,
          nullptr, nullptr);
    else
      g2_kernel<0><<<dim3(4, 32, G), 256, 0, stream>>>(
          Abf, yT, gcn_b + (long)l * HH, h0bf, nullptr, fmask, denom,
          graph_idx, out);
  }
}